// Round 1
// baseline (753.955 us; speedup 1.0000x reference)
//
#include <hip/hip_runtime.h>

#define N_NODES   50000
#define N_EDGES   600000
#define HID       128
#define N_GRAPHS  128
#define N_CLASSES 5

// --- degree (in-degree by dst, excluding self-loops) ---
__global__ void k_deg(const int* __restrict__ dst, int* __restrict__ ideg, int E) {
    int i = blockIdx.x * blockDim.x + threadIdx.x;
    if (i < E) atomicAdd(&ideg[dst[i]], 1);
}

// --- dis = 1/sqrt(deg + 1)  (self-loop makes deg>=1 always) ---
__global__ void k_dis(const int* __restrict__ ideg, float* __restrict__ dis, int n) {
    int i = blockIdx.x * blockDim.x + threadIdx.x;
    if (i < n) dis[i] = 1.0f / sqrtf((float)ideg[i] + 1.0f);
}

// --- single-block exclusive scan of ideg -> row_start[0..n] ---
__global__ void k_scan_nodes(const int* __restrict__ ideg, int* __restrict__ row_start, int n) {
    __shared__ int s[1024];
    int t = threadIdx.x;
    int C = (n + 1023) >> 10;
    int b = t * C, e = min(b + C, n);
    int local = 0;
    for (int i = b; i < e; ++i) local += ideg[i];
    s[t] = local;
    __syncthreads();
    for (int off = 1; off < 1024; off <<= 1) {
        int v = (t >= off) ? s[t - off] : 0;
        __syncthreads();
        s[t] += v;
        __syncthreads();
    }
    int prefix = s[t] - local;  // exclusive prefix
    for (int i = b; i < e; ++i) { row_start[i] = prefix; prefix += ideg[i]; }
    if (t == 1023) row_start[n] = prefix;
}

// --- CSR fill: col[] holds src of each incoming edge, grouped by dst ---
__global__ void k_fill(const int* __restrict__ src, const int* __restrict__ dst,
                       const int* __restrict__ row_start, int* __restrict__ cursor,
                       int* __restrict__ col, int E) {
    int i = blockIdx.x * blockDim.x + threadIdx.x;
    if (i < E) {
        int d = dst[i];
        int pos = atomicAdd(&cursor[d], 1);
        col[row_start[d] + pos] = src[i];
    }
}

// --- per-graph node counts (batch is sorted, graphs contiguous) ---
__global__ void k_gcnt(const int* __restrict__ batch, int* __restrict__ gcnt, int n) {
    int i = blockIdx.x * blockDim.x + threadIdx.x;
    if (i < n) atomicAdd(&gcnt[batch[i]], 1);
}

// --- exclusive scan of 128 graph counts -> start offsets ---
__global__ void k_scan_g(const int* __restrict__ gcnt, int* __restrict__ goff) {
    __shared__ int s[N_GRAPHS];
    int t = threadIdx.x;
    int v = gcnt[t];
    s[t] = v;
    __syncthreads();
    for (int off = 1; off < N_GRAPHS; off <<= 1) {
        int u = (t >= off) ? s[t - off] : 0;
        __syncthreads();
        s[t] += u;
        __syncthreads();
    }
    goff[t] = s[t] - v;
}

// --- layer-1 GEMM: out[i,f] = sum_{k<3} x[i,k] * W1[k,f] ---
__global__ void k_gemm_in(const float* __restrict__ x, const float* __restrict__ W,
                          float* __restrict__ out, int n) {
    int idx = blockIdx.x * blockDim.x + threadIdx.x;
    if (idx >= n * HID) return;
    int row = idx >> 7, f = idx & 127;
    float a = x[row * 3 + 0] * W[0 * HID + f];
    a = fmaf(x[row * 3 + 1], W[1 * HID + f], a);
    a = fmaf(x[row * 3 + 2], W[2 * HID + f], a);
    out[idx] = a;
}

// --- 128x128 GEMM: out = h @ W ; block covers 16 rows, thread = (col, row-half) ---
__global__ __launch_bounds__(256) void k_gemm128(const float* __restrict__ h,
                                                 const float* __restrict__ W,
                                                 float* __restrict__ out) {
    __shared__ float Hs[16 * HID];
    int tx = threadIdx.x & 127;
    int ty = threadIdx.x >> 7;
    int rb = blockIdx.x * 16;
    const float4* src4 = (const float4*)(h + (size_t)rb * HID);
    float4* Hs4 = (float4*)Hs;
    for (int i = threadIdx.x; i < 16 * HID / 4; i += 256) Hs4[i] = src4[i];
    __syncthreads();
    float acc[8] = {0, 0, 0, 0, 0, 0, 0, 0};
    for (int kc = 0; kc < HID; kc += 4) {
        float w0 = W[(kc + 0) * HID + tx];
        float w1 = W[(kc + 1) * HID + tx];
        float w2 = W[(kc + 2) * HID + tx];
        float w3 = W[(kc + 3) * HID + tx];
#pragma unroll
        for (int r = 0; r < 8; ++r) {
            float4 hv = *(const float4*)&Hs[(ty * 8 + r) * HID + kc];
            acc[r] = fmaf(hv.x, w0, acc[r]);
            acc[r] = fmaf(hv.y, w1, acc[r]);
            acc[r] = fmaf(hv.z, w2, acc[r]);
            acc[r] = fmaf(hv.w, w3, acc[r]);
        }
    }
#pragma unroll
    for (int r = 0; r < 8; ++r)
        out[(size_t)(rb + ty * 8 + r) * HID + tx] = acc[r];
}

// --- aggregation: out[d] = relu( dis[d]*sum_{s in N(d)} dis[s]*t[s] + dis[d]^2*t[d] + b ) ---
__global__ void k_agg(const float* __restrict__ t, const float* __restrict__ dis,
                      const int* __restrict__ row_start, const int* __restrict__ col,
                      const float* __restrict__ bias, float* __restrict__ out) {
    int d = blockIdx.x;
    int f = threadIdx.x;
    float dd = dis[d];
    int j0 = row_start[d], j1 = row_start[d + 1];
    float acc = 0.f;
    for (int j = j0; j < j1; ++j) {
        int s = col[j];
        acc = fmaf(dis[s], t[(size_t)s * HID + f], acc);
    }
    float v = fmaf(dd, acc, fmaf(dd * dd, t[(size_t)d * HID + f], bias[f]));
    out[(size_t)d * HID + f] = fmaxf(v, 0.f);
}

// --- per-graph mean pool (one block per graph) ---
__global__ void k_pool(const float* __restrict__ h, const int* __restrict__ gcnt,
                       const int* __restrict__ goff, float* __restrict__ fp) {
    int g = blockIdx.x, f = threadIdx.x;
    int start = goff[g], cnt = gcnt[g];
    float acc = 0.f;
    for (int i = 0; i < cnt; ++i) acc += h[(size_t)(start + i) * HID + f];
    fp[g * HID + f] = acc / (float)max(cnt, 1);
}

// --- final linear: out[g,c] = fp[g,:] @ Wl[:,c] + bl[c] ---
__global__ void k_final(const float* __restrict__ fp, const float* __restrict__ Wl,
                        const float* __restrict__ bl, float* __restrict__ out) {
    int idx = blockIdx.x * blockDim.x + threadIdx.x;
    if (idx >= N_GRAPHS * N_CLASSES) return;
    int g = idx / N_CLASSES, c = idx % N_CLASSES;
    float acc = bl[c];
    for (int f = 0; f < HID; ++f) acc = fmaf(fp[g * HID + f], Wl[f * N_CLASSES + c], acc);
    out[idx] = acc;
}

extern "C" void kernel_launch(void* const* d_in, const int* in_sizes, int n_in,
                              void* d_out, int out_size, void* d_ws, size_t ws_size,
                              hipStream_t stream) {
    const float* x     = (const float*)d_in[0];
    const int*   ei    = (const int*)d_in[1];   // [2, E]: row0 = src, row1 = dst
    const int*   batch = (const int*)d_in[2];
    const float* W1 = (const float*)d_in[3];
    const float* b1 = (const float*)d_in[4];
    const float* W2 = (const float*)d_in[5];
    const float* b2 = (const float*)d_in[6];
    const float* W3 = (const float*)d_in[7];
    const float* b3 = (const float*)d_in[8];
    const float* Wl = (const float*)d_in[9];
    const float* bl = (const float*)d_in[10];
    float* out = (float*)d_out;

    const int N = N_NODES, E = N_EDGES;
    const int* srcp = ei;
    const int* dstp = ei + E;

    char* ws = (char*)d_ws;
    size_t off = 0;
    auto alloc = [&](size_t bytes) -> void* {
        void* p = ws + off;
        off += (bytes + 255) & ~(size_t)255;
        return p;
    };
    // zero-initialized region must be first & contiguous (ws is poisoned 0xAA each call)
    int*   ideg   = (int*)alloc((size_t)N * 4);
    int*   cursor = (int*)alloc((size_t)N * 4);
    int*   gcnt   = (int*)alloc((size_t)N_GRAPHS * 4);
    size_t zero_bytes = off;
    float* dis  = (float*)alloc((size_t)N * 4);
    int*   rowst = (int*)alloc((size_t)(N + 1) * 4);
    int*   col   = (int*)alloc((size_t)E * 4);
    int*   goff  = (int*)alloc((size_t)N_GRAPHS * 4);
    float* fp    = (float*)alloc((size_t)N_GRAPHS * HID * 4);
    float* bufA  = (float*)alloc((size_t)N * HID * 4);
    float* bufB  = (float*)alloc((size_t)N * HID * 4);

    hipMemsetAsync(d_ws, 0, zero_bytes, stream);

    const int tpb = 256;
    k_deg<<<(E + tpb - 1) / tpb, tpb, 0, stream>>>(dstp, ideg, E);
    k_dis<<<(N + tpb - 1) / tpb, tpb, 0, stream>>>(ideg, dis, N);
    k_scan_nodes<<<1, 1024, 0, stream>>>(ideg, rowst, N);
    k_fill<<<(E + tpb - 1) / tpb, tpb, 0, stream>>>(srcp, dstp, rowst, cursor, col, E);
    k_gcnt<<<(N + tpb - 1) / tpb, tpb, 0, stream>>>(batch, gcnt, N);
    k_scan_g<<<1, N_GRAPHS, 0, stream>>>(gcnt, goff);

    // layer 1
    k_gemm_in<<<(N * HID + tpb - 1) / tpb, tpb, 0, stream>>>(x, W1, bufA, N);
    k_agg<<<N, HID, 0, stream>>>(bufA, dis, rowst, col, b1, bufB);
    // layer 2
    k_gemm128<<<N / 16, 256, 0, stream>>>(bufB, W2, bufA);
    k_agg<<<N, HID, 0, stream>>>(bufA, dis, rowst, col, b2, bufB);
    // layer 3
    k_gemm128<<<N / 16, 256, 0, stream>>>(bufB, W3, bufA);
    k_agg<<<N, HID, 0, stream>>>(bufA, dis, rowst, col, b3, bufB);
    // pool + classifier
    k_pool<<<N_GRAPHS, HID, 0, stream>>>(bufB, gcnt, goff, fp);
    k_final<<<(N_GRAPHS * N_CLASSES + tpb - 1) / tpb, tpb, 0, stream>>>(fp, Wl, bl, out);
}

// Round 2
// 633.761 us; speedup vs baseline: 1.1897x; 1.1897x over previous
//
#include <hip/hip_runtime.h>

#define N_NODES   50000
#define N_EDGES   600000
#define HID       128
#define N_GRAPHS  128
#define N_CLASSES 5

// --- degree (in-degree by dst, excluding self-loops) ---
__global__ void k_deg(const int* __restrict__ dst, int* __restrict__ ideg, int E) {
    int i = blockIdx.x * blockDim.x + threadIdx.x;
    if (i < E) atomicAdd(&ideg[dst[i]], 1);
}

// --- dis = 1/sqrt(deg + 1)  (self-loop makes deg>=1 always) ---
__global__ void k_dis(const int* __restrict__ ideg, float* __restrict__ dis, int n) {
    int i = blockIdx.x * blockDim.x + threadIdx.x;
    if (i < n) dis[i] = 1.0f / sqrtf((float)ideg[i] + 1.0f);
}

// --- single-block exclusive scan of ideg -> row_start[0..n] ---
__global__ void k_scan_nodes(const int* __restrict__ ideg, int* __restrict__ row_start, int n) {
    __shared__ int s[1024];
    int t = threadIdx.x;
    int C = (n + 1023) >> 10;
    int b = t * C, e = min(b + C, n);
    int local = 0;
    for (int i = b; i < e; ++i) local += ideg[i];
    s[t] = local;
    __syncthreads();
    for (int off = 1; off < 1024; off <<= 1) {
        int v = (t >= off) ? s[t - off] : 0;
        __syncthreads();
        s[t] += v;
        __syncthreads();
    }
    int prefix = s[t] - local;  // exclusive prefix
    for (int i = b; i < e; ++i) { row_start[i] = prefix; prefix += ideg[i]; }
    if (t == 1023) row_start[n] = prefix;
}

// --- CSR fill: col[] holds src of each incoming edge, grouped by dst ---
__global__ void k_fill(const int* __restrict__ src, const int* __restrict__ dst,
                       const int* __restrict__ row_start, int* __restrict__ cursor,
                       int* __restrict__ col, int E) {
    int i = blockIdx.x * blockDim.x + threadIdx.x;
    if (i < E) {
        int d = dst[i];
        int pos = atomicAdd(&cursor[d], 1);
        col[row_start[d] + pos] = src[i];
    }
}

// --- graph offsets via binary search on sorted batch (replaces atomic count + scan) ---
__global__ void k_goff(const int* __restrict__ batch, int* __restrict__ goff,
                       int* __restrict__ gcnt, int n) {
    __shared__ int s[N_GRAPHS + 1];
    int t = threadIdx.x;  // 256 threads, 0..128 active for search
    if (t <= N_GRAPHS) {
        int lo = 0, hi = n;
        while (lo < hi) {
            int mid = (lo + hi) >> 1;
            if (batch[mid] < t) lo = mid + 1; else hi = mid;
        }
        s[t] = lo;
        if (t < N_GRAPHS) goff[t] = lo;
    }
    __syncthreads();
    if (t < N_GRAPHS) gcnt[t] = s[t + 1] - s[t];
}

// --- layer-1 GEMM: out[i,f] = sum_{k<3} x[i,k] * W1[k,f] ---
__global__ void k_gemm_in(const float* __restrict__ x, const float* __restrict__ W,
                          float* __restrict__ out, int n) {
    int idx = blockIdx.x * blockDim.x + threadIdx.x;
    if (idx >= n * HID) return;
    int row = idx >> 7, f = idx & 127;
    float a = x[row * 3 + 0] * W[0 * HID + f];
    a = fmaf(x[row * 3 + 1], W[1 * HID + f], a);
    a = fmaf(x[row * 3 + 2], W[2 * HID + f], a);
    out[idx] = a;
}

// --- 128x128 GEMM: out = h @ W ; block covers 16 rows, thread = (col, row-half) ---
__global__ __launch_bounds__(256) void k_gemm128(const float* __restrict__ h,
                                                 const float* __restrict__ W,
                                                 float* __restrict__ out) {
    __shared__ float Hs[16 * HID];
    int tx = threadIdx.x & 127;
    int ty = threadIdx.x >> 7;
    int rb = blockIdx.x * 16;
    const float4* src4 = (const float4*)(h + (size_t)rb * HID);
    float4* Hs4 = (float4*)Hs;
    for (int i = threadIdx.x; i < 16 * HID / 4; i += 256) Hs4[i] = src4[i];
    __syncthreads();
    float acc[8] = {0, 0, 0, 0, 0, 0, 0, 0};
    for (int kc = 0; kc < HID; kc += 4) {
        float w0 = W[(kc + 0) * HID + tx];
        float w1 = W[(kc + 1) * HID + tx];
        float w2 = W[(kc + 2) * HID + tx];
        float w3 = W[(kc + 3) * HID + tx];
#pragma unroll
        for (int r = 0; r < 8; ++r) {
            float4 hv = *(const float4*)&Hs[(ty * 8 + r) * HID + kc];
            acc[r] = fmaf(hv.x, w0, acc[r]);
            acc[r] = fmaf(hv.y, w1, acc[r]);
            acc[r] = fmaf(hv.z, w2, acc[r]);
            acc[r] = fmaf(hv.w, w3, acc[r]);
        }
    }
#pragma unroll
    for (int r = 0; r < 8; ++r)
        out[(size_t)(rb + ty * 8 + r) * HID + tx] = acc[r];
}

// --- aggregation: out[d] = relu( dis[d]*sum_{s in N(d)} dis[s]*t[s] + dis[d]^2*t[d] + b ) ---
__global__ void k_agg(const float* __restrict__ t, const float* __restrict__ dis,
                      const int* __restrict__ row_start, const int* __restrict__ col,
                      const float* __restrict__ bias, float* __restrict__ out) {
    int d = blockIdx.x;
    int f = threadIdx.x;
    float dd = dis[d];
    int j0 = row_start[d], j1 = row_start[d + 1];
    float acc = 0.f;
    for (int j = j0; j < j1; ++j) {
        int s = col[j];
        acc = fmaf(dis[s], t[(size_t)s * HID + f], acc);
    }
    float v = fmaf(dd, acc, fmaf(dd * dd, t[(size_t)d * HID + f], bias[f]));
    out[(size_t)d * HID + f] = fmaxf(v, 0.f);
}

// --- per-graph mean pool (one block per graph) ---
__global__ void k_pool(const float* __restrict__ h, const int* __restrict__ gcnt,
                       const int* __restrict__ goff, float* __restrict__ fp) {
    int g = blockIdx.x, f = threadIdx.x;
    int start = goff[g], cnt = gcnt[g];
    float acc = 0.f;
    for (int i = 0; i < cnt; ++i) acc += h[(size_t)(start + i) * HID + f];
    fp[g * HID + f] = acc / (float)max(cnt, 1);
}

// --- final linear: out[g,c] = fp[g,:] @ Wl[:,c] + bl[c] ---
__global__ void k_final(const float* __restrict__ fp, const float* __restrict__ Wl,
                        const float* __restrict__ bl, float* __restrict__ out) {
    int idx = blockIdx.x * blockDim.x + threadIdx.x;
    if (idx >= N_GRAPHS * N_CLASSES) return;
    int g = idx / N_CLASSES, c = idx % N_CLASSES;
    float acc = bl[c];
    for (int f = 0; f < HID; ++f) acc = fmaf(fp[g * HID + f], Wl[f * N_CLASSES + c], acc);
    out[idx] = acc;
}

extern "C" void kernel_launch(void* const* d_in, const int* in_sizes, int n_in,
                              void* d_out, int out_size, void* d_ws, size_t ws_size,
                              hipStream_t stream) {
    const float* x     = (const float*)d_in[0];
    const int*   ei    = (const int*)d_in[1];   // [2, E]: row0 = src, row1 = dst
    const int*   batch = (const int*)d_in[2];
    const float* W1 = (const float*)d_in[3];
    const float* b1 = (const float*)d_in[4];
    const float* W2 = (const float*)d_in[5];
    const float* b2 = (const float*)d_in[6];
    const float* W3 = (const float*)d_in[7];
    const float* b3 = (const float*)d_in[8];
    const float* Wl = (const float*)d_in[9];
    const float* bl = (const float*)d_in[10];
    float* out = (float*)d_out;

    const int N = N_NODES, E = N_EDGES;
    const int* srcp = ei;
    const int* dstp = ei + E;

    char* ws = (char*)d_ws;
    size_t off = 0;
    auto alloc = [&](size_t bytes) -> void* {
        void* p = ws + off;
        off += (bytes + 255) & ~(size_t)255;
        return p;
    };
    // zero-initialized region must be first & contiguous (ws is poisoned 0xAA each call)
    int*   ideg   = (int*)alloc((size_t)N * 4);
    int*   cursor = (int*)alloc((size_t)N * 4);
    size_t zero_bytes = off;
    int*   gcnt  = (int*)alloc((size_t)N_GRAPHS * 4);
    float* dis   = (float*)alloc((size_t)N * 4);
    int*   rowst = (int*)alloc((size_t)(N + 1) * 4);
    int*   col   = (int*)alloc((size_t)E * 4);
    int*   goff  = (int*)alloc((size_t)N_GRAPHS * 4);
    float* fp    = (float*)alloc((size_t)N_GRAPHS * HID * 4);
    float* bufA  = (float*)alloc((size_t)N * HID * 4);
    float* bufB  = (float*)alloc((size_t)N * HID * 4);

    hipMemsetAsync(d_ws, 0, zero_bytes, stream);

    const int tpb = 256;
    k_deg<<<(E + tpb - 1) / tpb, tpb, 0, stream>>>(dstp, ideg, E);
    k_dis<<<(N + tpb - 1) / tpb, tpb, 0, stream>>>(ideg, dis, N);
    k_scan_nodes<<<1, 1024, 0, stream>>>(ideg, rowst, N);
    k_fill<<<(E + tpb - 1) / tpb, tpb, 0, stream>>>(srcp, dstp, rowst, cursor, col, E);
    k_goff<<<1, 256, 0, stream>>>(batch, goff, gcnt, N);

    // layer 1
    k_gemm_in<<<(N * HID + tpb - 1) / tpb, tpb, 0, stream>>>(x, W1, bufA, N);
    k_agg<<<N, HID, 0, stream>>>(bufA, dis, rowst, col, b1, bufB);
    // layer 2
    k_gemm128<<<N / 16, 256, 0, stream>>>(bufB, W2, bufA);
    k_agg<<<N, HID, 0, stream>>>(bufA, dis, rowst, col, b2, bufB);
    // layer 3
    k_gemm128<<<N / 16, 256, 0, stream>>>(bufB, W3, bufA);
    k_agg<<<N, HID, 0, stream>>>(bufA, dis, rowst, col, b3, bufB);
    // pool + classifier
    k_pool<<<N_GRAPHS, HID, 0, stream>>>(bufB, gcnt, goff, fp);
    k_final<<<(N_GRAPHS * N_CLASSES + tpb - 1) / tpb, tpb, 0, stream>>>(fp, Wl, bl, out);
}

// Round 3
// 567.333 us; speedup vs baseline: 1.3289x; 1.1171x over previous
//
#include <hip/hip_runtime.h>

#define N_NODES   50000
#define N_EDGES   600000
#define HID       128
#define N_GRAPHS  128
#define N_CLASSES 5
#define POOL_CHUNK 128

// --- degree (in-degree by dst, excluding self-loops) ---
__global__ void k_deg(const int* __restrict__ dst, int* __restrict__ ideg, int E) {
    int i = blockIdx.x * blockDim.x + threadIdx.x;
    if (i < E) atomicAdd(&ideg[dst[i]], 1);
}

// --- dis = 1/sqrt(deg + 1)  (self-loop makes deg>=1 always) ---
__global__ void k_dis(const int* __restrict__ ideg, float* __restrict__ dis, int n) {
    int i = blockIdx.x * blockDim.x + threadIdx.x;
    if (i < n) dis[i] = 1.0f / sqrtf((float)ideg[i] + 1.0f);
}

// --- single-block exclusive scan of ideg -> row_start[0..n] ---
__global__ void k_scan_nodes(const int* __restrict__ ideg, int* __restrict__ row_start, int n) {
    __shared__ int s[1024];
    int t = threadIdx.x;
    int C = (n + 1023) >> 10;
    int b = t * C, e = min(b + C, n);
    int local = 0;
    for (int i = b; i < e; ++i) local += ideg[i];
    s[t] = local;
    __syncthreads();
    for (int off = 1; off < 1024; off <<= 1) {
        int v = (t >= off) ? s[t - off] : 0;
        __syncthreads();
        s[t] += v;
        __syncthreads();
    }
    int prefix = s[t] - local;  // exclusive prefix
    for (int i = b; i < e; ++i) { row_start[i] = prefix; prefix += ideg[i]; }
    if (t == 1023) row_start[n] = prefix;
}

// --- CSR fill: col[] holds src of each incoming edge, grouped by dst ---
__global__ void k_fill(const int* __restrict__ src, const int* __restrict__ dst,
                       const int* __restrict__ row_start, int* __restrict__ cursor,
                       int* __restrict__ col, int E) {
    int i = blockIdx.x * blockDim.x + threadIdx.x;
    if (i < E) {
        int d = dst[i];
        int pos = atomicAdd(&cursor[d], 1);
        col[row_start[d] + pos] = src[i];
    }
}

// --- graph offsets via binary search on sorted batch ---
__global__ void k_goff(const int* __restrict__ batch, int* __restrict__ goff,
                       int* __restrict__ gcnt, int n) {
    __shared__ int s[N_GRAPHS + 1];
    int t = threadIdx.x;
    if (t <= N_GRAPHS) {
        int lo = 0, hi = n;
        while (lo < hi) {
            int mid = (lo + hi) >> 1;
            if (batch[mid] < t) lo = mid + 1; else hi = mid;
        }
        s[t] = lo;
        if (t < N_GRAPHS) goff[t] = lo;
    }
    __syncthreads();
    if (t < N_GRAPHS) gcnt[t] = s[t + 1] - s[t];
}

// --- layer-1 GEMM: out[i,f] = sum_{k<3} x[i,k] * W1[k,f] ---
__global__ void k_gemm_in(const float* __restrict__ x, const float* __restrict__ W,
                          float* __restrict__ out, int n) {
    int idx = blockIdx.x * blockDim.x + threadIdx.x;
    if (idx >= n * HID) return;
    int row = idx >> 7, f = idx & 127;
    float a = x[row * 3 + 0] * W[0 * HID + f];
    a = fmaf(x[row * 3 + 1], W[1 * HID + f], a);
    a = fmaf(x[row * 3 + 2], W[2 * HID + f], a);
    out[idx] = a;
}

// --- 128x128 GEMM: out = h @ W ---
__global__ __launch_bounds__(256) void k_gemm128(const float* __restrict__ h,
                                                 const float* __restrict__ W,
                                                 float* __restrict__ out) {
    __shared__ float Hs[16 * HID];
    int tx = threadIdx.x & 127;
    int ty = threadIdx.x >> 7;
    int rb = blockIdx.x * 16;
    const float4* src4 = (const float4*)(h + (size_t)rb * HID);
    float4* Hs4 = (float4*)Hs;
    for (int i = threadIdx.x; i < 16 * HID / 4; i += 256) Hs4[i] = src4[i];
    __syncthreads();
    float acc[8] = {0, 0, 0, 0, 0, 0, 0, 0};
    for (int kc = 0; kc < HID; kc += 4) {
        float w0 = W[(kc + 0) * HID + tx];
        float w1 = W[(kc + 1) * HID + tx];
        float w2 = W[(kc + 2) * HID + tx];
        float w3 = W[(kc + 3) * HID + tx];
#pragma unroll
        for (int r = 0; r < 8; ++r) {
            float4 hv = *(const float4*)&Hs[(ty * 8 + r) * HID + kc];
            acc[r] = fmaf(hv.x, w0, acc[r]);
            acc[r] = fmaf(hv.y, w1, acc[r]);
            acc[r] = fmaf(hv.z, w2, acc[r]);
            acc[r] = fmaf(hv.w, w3, acc[r]);
        }
    }
#pragma unroll
    for (int r = 0; r < 8; ++r)
        out[(size_t)(rb + ty * 8 + r) * HID + tx] = acc[r];
}

// --- aggregation: out[d] = relu( dis[d]*sum_{s in N(d)} dis[s]*t[s] + dis[d]^2*t[d] + b ) ---
__global__ void k_agg(const float* __restrict__ t, const float* __restrict__ dis,
                      const int* __restrict__ row_start, const int* __restrict__ col,
                      const float* __restrict__ bias, float* __restrict__ out) {
    int d = blockIdx.x;
    int f = threadIdx.x;
    float dd = dis[d];
    int j0 = row_start[d], j1 = row_start[d + 1];
    float acc = 0.f;
    for (int j = j0; j < j1; ++j) {
        int s = col[j];
        acc = fmaf(dis[s], t[(size_t)s * HID + f], acc);
    }
    float v = fmaf(dd, acc, fmaf(dd * dd, t[(size_t)d * HID + f], bias[f]));
    out[(size_t)d * HID + f] = fmaxf(v, 0.f);
}

// --- node-parallel pool partial sums: fpsum[g,f] += sum over chunk rows ---
__global__ void k_psum(const float* __restrict__ h, const int* __restrict__ batch,
                       float* __restrict__ fpsum, int n) {
    int i0 = blockIdx.x * POOL_CHUNK;
    int f = threadIdx.x;
    int end = min(i0 + POOL_CHUNK, n);
    int cur = batch[i0];
    float acc = 0.f;
    for (int i = i0; i < end; ++i) {
        int g = batch[i];
        if (g != cur) {  // graph boundary (rare: batch sorted, ~390 nodes/graph)
            atomicAdd(&fpsum[cur * HID + f], acc);
            acc = 0.f;
            cur = g;
        }
        acc += h[(size_t)i * HID + f];
    }
    atomicAdd(&fpsum[cur * HID + f], acc);
}

// --- final linear with mean folded in: out[g,c] = (fpsum[g,:]/cnt) @ Wl[:,c] + bl[c] ---
__global__ void k_final(const float* __restrict__ fpsum, const int* __restrict__ gcnt,
                        const float* __restrict__ Wl, const float* __restrict__ bl,
                        float* __restrict__ out) {
    int idx = blockIdx.x * blockDim.x + threadIdx.x;
    if (idx >= N_GRAPHS * N_CLASSES) return;
    int g = idx / N_CLASSES, c = idx % N_CLASSES;
    float inv = 1.0f / (float)max(gcnt[g], 1);
    float acc = bl[c];
    for (int f = 0; f < HID; ++f)
        acc = fmaf(fpsum[g * HID + f] * inv, Wl[f * N_CLASSES + c], acc);
    out[idx] = acc;
}

extern "C" void kernel_launch(void* const* d_in, const int* in_sizes, int n_in,
                              void* d_out, int out_size, void* d_ws, size_t ws_size,
                              hipStream_t stream) {
    const float* x     = (const float*)d_in[0];
    const int*   ei    = (const int*)d_in[1];   // [2, E]: row0 = src, row1 = dst
    const int*   batch = (const int*)d_in[2];
    const float* W1 = (const float*)d_in[3];
    const float* b1 = (const float*)d_in[4];
    const float* W2 = (const float*)d_in[5];
    const float* b2 = (const float*)d_in[6];
    const float* W3 = (const float*)d_in[7];
    const float* b3 = (const float*)d_in[8];
    const float* Wl = (const float*)d_in[9];
    const float* bl = (const float*)d_in[10];
    float* out = (float*)d_out;

    const int N = N_NODES, E = N_EDGES;
    const int* srcp = ei;
    const int* dstp = ei + E;

    char* ws = (char*)d_ws;
    size_t off = 0;
    auto alloc = [&](size_t bytes) -> void* {
        void* p = ws + off;
        off += (bytes + 255) & ~(size_t)255;
        return p;
    };
    // zero-initialized region must be first & contiguous (ws is poisoned 0xAA each call)
    int*   ideg   = (int*)alloc((size_t)N * 4);
    int*   cursor = (int*)alloc((size_t)N * 4);
    float* fpsum  = (float*)alloc((size_t)N_GRAPHS * HID * 4);
    size_t zero_bytes = off;
    int*   gcnt  = (int*)alloc((size_t)N_GRAPHS * 4);
    float* dis   = (float*)alloc((size_t)N * 4);
    int*   rowst = (int*)alloc((size_t)(N + 1) * 4);
    int*   col   = (int*)alloc((size_t)E * 4);
    int*   goff  = (int*)alloc((size_t)N_GRAPHS * 4);
    float* bufA  = (float*)alloc((size_t)N * HID * 4);
    float* bufB  = (float*)alloc((size_t)N * HID * 4);

    hipMemsetAsync(d_ws, 0, zero_bytes, stream);

    const int tpb = 256;
    k_deg<<<(E + tpb - 1) / tpb, tpb, 0, stream>>>(dstp, ideg, E);
    k_dis<<<(N + tpb - 1) / tpb, tpb, 0, stream>>>(ideg, dis, N);
    k_scan_nodes<<<1, 1024, 0, stream>>>(ideg, rowst, N);
    k_fill<<<(E + tpb - 1) / tpb, tpb, 0, stream>>>(srcp, dstp, rowst, cursor, col, E);
    k_goff<<<1, 256, 0, stream>>>(batch, goff, gcnt, N);

    // layer 1
    k_gemm_in<<<(N * HID + tpb - 1) / tpb, tpb, 0, stream>>>(x, W1, bufA, N);
    k_agg<<<N, HID, 0, stream>>>(bufA, dis, rowst, col, b1, bufB);
    // layer 2
    k_gemm128<<<N / 16, 256, 0, stream>>>(bufB, W2, bufA);
    k_agg<<<N, HID, 0, stream>>>(bufA, dis, rowst, col, b2, bufB);
    // layer 3
    k_gemm128<<<N / 16, 256, 0, stream>>>(bufB, W3, bufA);
    k_agg<<<N, HID, 0, stream>>>(bufA, dis, rowst, col, b3, bufB);
    // pool + classifier
    k_psum<<<(N + POOL_CHUNK - 1) / POOL_CHUNK, HID, 0, stream>>>(bufB, batch, fpsum, N);
    k_final<<<(N_GRAPHS * N_CLASSES + tpb - 1) / tpb, tpb, 0, stream>>>(fpsum, gcnt, Wl, bl, out);
}

// Round 4
// 497.467 us; speedup vs baseline: 1.5156x; 1.1404x over previous
//
#include <hip/hip_runtime.h>

#define N_NODES   50000
#define N_EDGES   600000
#define HID       128
#define N_GRAPHS  128
#define N_CLASSES 5
#define POOL_CHUNK 128
#define SCAN_BLK  ((N_NODES + 255) / 256)   // 196

// --- degree (in-degree by dst, excluding self-loops) ---
__global__ void k_deg(const int* __restrict__ dst, int* __restrict__ ideg, int E) {
    int i = blockIdx.x * blockDim.x + threadIdx.x;
    if (i < E) atomicAdd(&ideg[dst[i]], 1);
}

// --- dis = 1/sqrt(deg + 1)  (self-loop makes deg>=1 always) ---
__global__ void k_dis(const int* __restrict__ ideg, float* __restrict__ dis, int n) {
    int i = blockIdx.x * blockDim.x + threadIdx.x;
    if (i < n) dis[i] = 1.0f / sqrtf((float)ideg[i] + 1.0f);
}

// --- 3-phase hierarchical scan of ideg -> row_start[0..n] ---
__global__ void k_scan_part(const int* __restrict__ ideg, int* __restrict__ bsum, int n) {
    __shared__ int s[256];
    int t = threadIdx.x;
    int i = blockIdx.x * 256 + t;
    s[t] = (i < n) ? ideg[i] : 0;
    __syncthreads();
    for (int off = 128; off > 0; off >>= 1) {
        if (t < off) s[t] += s[t + off];
        __syncthreads();
    }
    if (t == 0) bsum[blockIdx.x] = s[0];
}

__global__ void k_scan_bsum(const int* __restrict__ bsum, int* __restrict__ boff, int B) {
    __shared__ int s[256];
    int t = threadIdx.x;
    int v = (t < B) ? bsum[t] : 0;
    s[t] = v;
    __syncthreads();
    for (int off = 1; off < 256; off <<= 1) {
        int u = (t >= off) ? s[t - off] : 0;
        __syncthreads();
        s[t] += u;
        __syncthreads();
    }
    if (t < B) boff[t] = s[t] - v;
    if (t == 255) boff[B] = s[255];  // grand total
}

__global__ void k_scan_write(const int* __restrict__ ideg, const int* __restrict__ boff,
                             int* __restrict__ row_start, int n, int B) {
    __shared__ int s[256];
    int t = threadIdx.x;
    int i = blockIdx.x * 256 + t;
    int v = (i < n) ? ideg[i] : 0;
    s[t] = v;
    __syncthreads();
    for (int off = 1; off < 256; off <<= 1) {
        int u = (t >= off) ? s[t - off] : 0;
        __syncthreads();
        s[t] += u;
        __syncthreads();
    }
    if (i < n) row_start[i] = boff[blockIdx.x] + s[t] - v;
    if (blockIdx.x == 0 && t == 0) row_start[n] = boff[B];
}

// --- CSR fill: col[] holds src of each incoming edge, grouped by dst ---
__global__ void k_fill(const int* __restrict__ src, const int* __restrict__ dst,
                       const int* __restrict__ row_start, int* __restrict__ cursor,
                       int* __restrict__ col, int E) {
    int i = blockIdx.x * blockDim.x + threadIdx.x;
    if (i < E) {
        int d = dst[i];
        int pos = atomicAdd(&cursor[d], 1);
        col[row_start[d] + pos] = src[i];
    }
}

// --- graph offsets via binary search on sorted batch ---
__global__ void k_goff(const int* __restrict__ batch, int* __restrict__ goff,
                       int* __restrict__ gcnt, int n) {
    __shared__ int s[N_GRAPHS + 1];
    int t = threadIdx.x;
    if (t <= N_GRAPHS) {
        int lo = 0, hi = n;
        while (lo < hi) {
            int mid = (lo + hi) >> 1;
            if (batch[mid] < t) lo = mid + 1; else hi = mid;
        }
        s[t] = lo;
        if (t < N_GRAPHS) goff[t] = lo;
    }
    __syncthreads();
    if (t < N_GRAPHS) gcnt[t] = s[t + 1] - s[t];
}

// --- layer-1 GEMM: out[i,f] = sum_{k<3} x[i,k] * W1[k,f] ---
__global__ void k_gemm_in(const float* __restrict__ x, const float* __restrict__ W,
                          float* __restrict__ out, int n) {
    int idx = blockIdx.x * blockDim.x + threadIdx.x;
    if (idx >= n * HID) return;
    int row = idx >> 7, f = idx & 127;
    float a = x[row * 3 + 0] * W[0 * HID + f];
    a = fmaf(x[row * 3 + 1], W[1 * HID + f], a);
    a = fmaf(x[row * 3 + 2], W[2 * HID + f], a);
    out[idx] = a;
}

// --- 128x128 GEMM: out = h @ W ---
__global__ __launch_bounds__(256) void k_gemm128(const float* __restrict__ h,
                                                 const float* __restrict__ W,
                                                 float* __restrict__ out) {
    __shared__ float Hs[16 * HID];
    int tx = threadIdx.x & 127;
    int ty = threadIdx.x >> 7;
    int rb = blockIdx.x * 16;
    const float4* src4 = (const float4*)(h + (size_t)rb * HID);
    float4* Hs4 = (float4*)Hs;
    for (int i = threadIdx.x; i < 16 * HID / 4; i += 256) Hs4[i] = src4[i];
    __syncthreads();
    float acc[8] = {0, 0, 0, 0, 0, 0, 0, 0};
    for (int kc = 0; kc < HID; kc += 4) {
        float w0 = W[(kc + 0) * HID + tx];
        float w1 = W[(kc + 1) * HID + tx];
        float w2 = W[(kc + 2) * HID + tx];
        float w3 = W[(kc + 3) * HID + tx];
#pragma unroll
        for (int r = 0; r < 8; ++r) {
            float4 hv = *(const float4*)&Hs[(ty * 8 + r) * HID + kc];
            acc[r] = fmaf(hv.x, w0, acc[r]);
            acc[r] = fmaf(hv.y, w1, acc[r]);
            acc[r] = fmaf(hv.z, w2, acc[r]);
            acc[r] = fmaf(hv.w, w3, acc[r]);
        }
    }
#pragma unroll
    for (int r = 0; r < 8; ++r)
        out[(size_t)(rb + ty * 8 + r) * HID + tx] = acc[r];
}

// --- aggregation: out[d] = relu( dis[d]*sum_{s in N(d)} dis[s]*t[s] + dis[d]^2*t[d] + b ) ---
__global__ void k_agg(const float* __restrict__ t, const float* __restrict__ dis,
                      const int* __restrict__ row_start, const int* __restrict__ col,
                      const float* __restrict__ bias, float* __restrict__ out) {
    int d = blockIdx.x;
    int f = threadIdx.x;
    float dd = dis[d];
    int j0 = row_start[d], j1 = row_start[d + 1];
    float acc = 0.f;
    for (int j = j0; j < j1; ++j) {
        int s = col[j];
        acc = fmaf(dis[s], t[(size_t)s * HID + f], acc);
    }
    float v = fmaf(dd, acc, fmaf(dd * dd, t[(size_t)d * HID + f], bias[f]));
    out[(size_t)d * HID + f] = fmaxf(v, 0.f);
}

// --- node-parallel pool partial sums ---
__global__ void k_psum(const float* __restrict__ h, const int* __restrict__ batch,
                       float* __restrict__ fpsum, int n) {
    int i0 = blockIdx.x * POOL_CHUNK;
    int f = threadIdx.x;
    int end = min(i0 + POOL_CHUNK, n);
    int cur = batch[i0];
    float acc = 0.f;
    for (int i = i0; i < end; ++i) {
        int g = batch[i];
        if (g != cur) {
            atomicAdd(&fpsum[cur * HID + f], acc);
            acc = 0.f;
            cur = g;
        }
        acc += h[(size_t)i * HID + f];
    }
    atomicAdd(&fpsum[cur * HID + f], acc);
}

// --- final linear with mean folded in ---
__global__ void k_final(const float* __restrict__ fpsum, const int* __restrict__ gcnt,
                        const float* __restrict__ Wl, const float* __restrict__ bl,
                        float* __restrict__ out) {
    int idx = blockIdx.x * blockDim.x + threadIdx.x;
    if (idx >= N_GRAPHS * N_CLASSES) return;
    int g = idx / N_CLASSES, c = idx % N_CLASSES;
    float inv = 1.0f / (float)max(gcnt[g], 1);
    float acc = bl[c];
    for (int f = 0; f < HID; ++f)
        acc = fmaf(fpsum[g * HID + f] * inv, Wl[f * N_CLASSES + c], acc);
    out[idx] = acc;
}

extern "C" void kernel_launch(void* const* d_in, const int* in_sizes, int n_in,
                              void* d_out, int out_size, void* d_ws, size_t ws_size,
                              hipStream_t stream) {
    const float* x     = (const float*)d_in[0];
    const int*   ei    = (const int*)d_in[1];   // [2, E]: row0 = src, row1 = dst
    const int*   batch = (const int*)d_in[2];
    const float* W1 = (const float*)d_in[3];
    const float* b1 = (const float*)d_in[4];
    const float* W2 = (const float*)d_in[5];
    const float* b2 = (const float*)d_in[6];
    const float* W3 = (const float*)d_in[7];
    const float* b3 = (const float*)d_in[8];
    const float* Wl = (const float*)d_in[9];
    const float* bl = (const float*)d_in[10];
    float* out = (float*)d_out;

    const int N = N_NODES, E = N_EDGES;
    const int* srcp = ei;
    const int* dstp = ei + E;

    char* ws = (char*)d_ws;
    size_t off = 0;
    auto alloc = [&](size_t bytes) -> void* {
        void* p = ws + off;
        off += (bytes + 255) & ~(size_t)255;
        return p;
    };
    // zero-initialized region must be first & contiguous (ws is poisoned 0xAA each call)
    int*   ideg   = (int*)alloc((size_t)N * 4);
    int*   cursor = (int*)alloc((size_t)N * 4);
    float* fpsum  = (float*)alloc((size_t)N_GRAPHS * HID * 4);
    size_t zero_bytes = off;
    int*   gcnt  = (int*)alloc((size_t)N_GRAPHS * 4);
    float* dis   = (float*)alloc((size_t)N * 4);
    int*   rowst = (int*)alloc((size_t)(N + 1) * 4);
    int*   col   = (int*)alloc((size_t)E * 4);
    int*   goff  = (int*)alloc((size_t)N_GRAPHS * 4);
    int*   bsum  = (int*)alloc((size_t)SCAN_BLK * 4);
    int*   boff  = (int*)alloc((size_t)(SCAN_BLK + 1) * 4);
    float* bufA  = (float*)alloc((size_t)N * HID * 4);
    float* bufB  = (float*)alloc((size_t)N * HID * 4);

    hipMemsetAsync(d_ws, 0, zero_bytes, stream);

    const int tpb = 256;
    k_deg<<<(E + tpb - 1) / tpb, tpb, 0, stream>>>(dstp, ideg, E);
    k_dis<<<(N + tpb - 1) / tpb, tpb, 0, stream>>>(ideg, dis, N);
    k_scan_part<<<SCAN_BLK, 256, 0, stream>>>(ideg, bsum, N);
    k_scan_bsum<<<1, 256, 0, stream>>>(bsum, boff, SCAN_BLK);
    k_scan_write<<<SCAN_BLK, 256, 0, stream>>>(ideg, boff, rowst, N, SCAN_BLK);
    k_fill<<<(E + tpb - 1) / tpb, tpb, 0, stream>>>(srcp, dstp, rowst, cursor, col, E);
    k_goff<<<1, 256, 0, stream>>>(batch, goff, gcnt, N);

    // layer 1
    k_gemm_in<<<(N * HID + tpb - 1) / tpb, tpb, 0, stream>>>(x, W1, bufA, N);
    k_agg<<<N, HID, 0, stream>>>(bufA, dis, rowst, col, b1, bufB);
    // layer 2
    k_gemm128<<<N / 16, 256, 0, stream>>>(bufB, W2, bufA);
    k_agg<<<N, HID, 0, stream>>>(bufA, dis, rowst, col, b2, bufB);
    // layer 3
    k_gemm128<<<N / 16, 256, 0, stream>>>(bufB, W3, bufA);
    k_agg<<<N, HID, 0, stream>>>(bufA, dis, rowst, col, b3, bufB);
    // pool + classifier
    k_psum<<<(N + POOL_CHUNK - 1) / POOL_CHUNK, HID, 0, stream>>>(bufB, batch, fpsum, N);
    k_final<<<(N_GRAPHS * N_CLASSES + tpb - 1) / tpb, tpb, 0, stream>>>(fpsum, gcnt, Wl, bl, out);
}

// Round 5
// 421.120 us; speedup vs baseline: 1.7904x; 1.1813x over previous
//
#include <hip/hip_runtime.h>

#define N_NODES   50000
#define N_EDGES   600000
#define HID       128
#define N_GRAPHS  128
#define N_CLASSES 5
#define POOL_CHUNK 128
#define SCAN_BLK  ((N_NODES + 255) / 256)   // 196

// --- degree (in-degree by dst, excluding self-loops) ---
__global__ void k_deg(const int* __restrict__ dst, int* __restrict__ ideg, int E) {
    int i = blockIdx.x * blockDim.x + threadIdx.x;
    if (i < E) atomicAdd(&ideg[dst[i]], 1);
}

// --- dis = 1/sqrt(deg + 1)  (self-loop makes deg>=1 always) ---
__global__ void k_dis(const int* __restrict__ ideg, float* __restrict__ dis, int n) {
    int i = blockIdx.x * blockDim.x + threadIdx.x;
    if (i < n) dis[i] = 1.0f / sqrtf((float)ideg[i] + 1.0f);
}

// --- 3-phase hierarchical scan of ideg -> row_start[0..n] ---
__global__ void k_scan_part(const int* __restrict__ ideg, int* __restrict__ bsum, int n) {
    __shared__ int s[256];
    int t = threadIdx.x;
    int i = blockIdx.x * 256 + t;
    s[t] = (i < n) ? ideg[i] : 0;
    __syncthreads();
    for (int off = 128; off > 0; off >>= 1) {
        if (t < off) s[t] += s[t + off];
        __syncthreads();
    }
    if (t == 0) bsum[blockIdx.x] = s[0];
}

__global__ void k_scan_bsum(const int* __restrict__ bsum, int* __restrict__ boff, int B) {
    __shared__ int s[256];
    int t = threadIdx.x;
    int v = (t < B) ? bsum[t] : 0;
    s[t] = v;
    __syncthreads();
    for (int off = 1; off < 256; off <<= 1) {
        int u = (t >= off) ? s[t - off] : 0;
        __syncthreads();
        s[t] += u;
        __syncthreads();
    }
    if (t < B) boff[t] = s[t] - v;
    if (t == 255) boff[B] = s[255];  // grand total
}

__global__ void k_scan_write(const int* __restrict__ ideg, const int* __restrict__ boff,
                             int* __restrict__ row_start, int n, int B) {
    __shared__ int s[256];
    int t = threadIdx.x;
    int i = blockIdx.x * 256 + t;
    int v = (i < n) ? ideg[i] : 0;
    s[t] = v;
    __syncthreads();
    for (int off = 1; off < 256; off <<= 1) {
        int u = (t >= off) ? s[t - off] : 0;
        __syncthreads();
        s[t] += u;
        __syncthreads();
    }
    if (i < n) row_start[i] = boff[blockIdx.x] + s[t] - v;
    if (blockIdx.x == 0 && t == 0) row_start[n] = boff[B];
}

// --- CSR fill: col[] holds src of each incoming edge, grouped by dst ---
__global__ void k_fill(const int* __restrict__ src, const int* __restrict__ dst,
                       const int* __restrict__ row_start, int* __restrict__ cursor,
                       int* __restrict__ col, int E) {
    int i = blockIdx.x * blockDim.x + threadIdx.x;
    if (i < E) {
        int d = dst[i];
        int pos = atomicAdd(&cursor[d], 1);
        col[row_start[d] + pos] = src[i];
    }
}

// --- graph offsets via binary search on sorted batch ---
__global__ void k_goff(const int* __restrict__ batch, int* __restrict__ goff,
                       int* __restrict__ gcnt, int n) {
    __shared__ int s[N_GRAPHS + 1];
    int t = threadIdx.x;
    if (t <= N_GRAPHS) {
        int lo = 0, hi = n;
        while (lo < hi) {
            int mid = (lo + hi) >> 1;
            if (batch[mid] < t) lo = mid + 1; else hi = mid;
        }
        s[t] = lo;
        if (t < N_GRAPHS) goff[t] = lo;
    }
    __syncthreads();
    if (t < N_GRAPHS) gcnt[t] = s[t + 1] - s[t];
}

// --- layer-1 GEMM with dis pre-scale: out[i,f] = dis[i] * (x@W1)[i,f] ---
__global__ void k_gemm_in(const float* __restrict__ x, const float* __restrict__ W,
                          const float* __restrict__ dis, float* __restrict__ out, int n) {
    int idx = blockIdx.x * blockDim.x + threadIdx.x;
    if (idx >= n * HID) return;
    int row = idx >> 7, f = idx & 127;
    float a = x[row * 3 + 0] * W[0 * HID + f];
    a = fmaf(x[row * 3 + 1], W[1 * HID + f], a);
    a = fmaf(x[row * 3 + 2], W[2 * HID + f], a);
    out[idx] = dis[row] * a;
}

// --- 128x128 GEMM with dis pre-scale: out = dis[:,None] * (h @ W) ---
__global__ __launch_bounds__(256) void k_gemm128(const float* __restrict__ h,
                                                 const float* __restrict__ W,
                                                 const float* __restrict__ dis,
                                                 float* __restrict__ out) {
    __shared__ float Hs[16 * HID];
    int tx = threadIdx.x & 127;
    int ty = threadIdx.x >> 7;
    int rb = blockIdx.x * 16;
    const float4* src4 = (const float4*)(h + (size_t)rb * HID);
    float4* Hs4 = (float4*)Hs;
    for (int i = threadIdx.x; i < 16 * HID / 4; i += 256) Hs4[i] = src4[i];
    __syncthreads();
    float acc[8] = {0, 0, 0, 0, 0, 0, 0, 0};
    for (int kc = 0; kc < HID; kc += 4) {
        float w0 = W[(kc + 0) * HID + tx];
        float w1 = W[(kc + 1) * HID + tx];
        float w2 = W[(kc + 2) * HID + tx];
        float w3 = W[(kc + 3) * HID + tx];
#pragma unroll
        for (int r = 0; r < 8; ++r) {
            float4 hv = *(const float4*)&Hs[(ty * 8 + r) * HID + kc];
            acc[r] = fmaf(hv.x, w0, acc[r]);
            acc[r] = fmaf(hv.y, w1, acc[r]);
            acc[r] = fmaf(hv.z, w2, acc[r]);
            acc[r] = fmaf(hv.w, w3, acc[r]);
        }
    }
#pragma unroll
    for (int r = 0; r < 8; ++r) {
        int row = rb + ty * 8 + r;
        out[(size_t)row * HID + tx] = dis[row] * acc[r];
    }
}

// --- aggregation on pre-scaled t: out[d] = relu( dis[d] * (t[d] + sum_{s in N(d)} t[s]) + b )
// wave-per-dst (4 dst per 256-thread block), float2 lanes, 4-way edge unroll for MLP.
__global__ __launch_bounds__(256) void k_agg(const float* __restrict__ t,
                                             const float* __restrict__ dis,
                                             const int* __restrict__ row_start,
                                             const int* __restrict__ col,
                                             const float* __restrict__ bias,
                                             float* __restrict__ out) {
    int lane = threadIdx.x & 63;
    int wid  = threadIdx.x >> 6;
    int d = blockIdx.x * 4 + wid;
    if (d >= N_NODES) return;
    const float2* t2 = (const float2*)t;
    float2 bv = ((const float2*)bias)[lane];
    float dd = dis[d];
    int j0 = row_start[d], j1 = row_start[d + 1];
    float2 self = t2[(size_t)d * 64 + lane];
    float ax0 = self.x, ay0 = self.y;
    float ax1 = 0.f, ay1 = 0.f, ax2 = 0.f, ay2 = 0.f, ax3 = 0.f, ay3 = 0.f;
    int j = j0;
    for (; j + 3 < j1; j += 4) {
        int s0 = col[j], s1 = col[j + 1], s2 = col[j + 2], s3 = col[j + 3];
        float2 v0 = t2[(size_t)s0 * 64 + lane];
        float2 v1 = t2[(size_t)s1 * 64 + lane];
        float2 v2 = t2[(size_t)s2 * 64 + lane];
        float2 v3 = t2[(size_t)s3 * 64 + lane];
        ax0 += v0.x; ay0 += v0.y;
        ax1 += v1.x; ay1 += v1.y;
        ax2 += v2.x; ay2 += v2.y;
        ax3 += v3.x; ay3 += v3.y;
    }
    for (; j < j1; ++j) {
        int s = col[j];
        float2 v = t2[(size_t)s * 64 + lane];
        ax0 += v.x; ay0 += v.y;
    }
    float sx = (ax0 + ax1) + (ax2 + ax3);
    float sy = (ay0 + ay1) + (ay2 + ay3);
    float2 o;
    o.x = fmaxf(fmaf(dd, sx, bv.x), 0.f);
    o.y = fmaxf(fmaf(dd, sy, bv.y), 0.f);
    ((float2*)out)[(size_t)d * 64 + lane] = o;
}

// --- node-parallel pool partial sums ---
__global__ void k_psum(const float* __restrict__ h, const int* __restrict__ batch,
                       float* __restrict__ fpsum, int n) {
    int i0 = blockIdx.x * POOL_CHUNK;
    int f = threadIdx.x;
    int end = min(i0 + POOL_CHUNK, n);
    int cur = batch[i0];
    float acc = 0.f;
    for (int i = i0; i < end; ++i) {
        int g = batch[i];
        if (g != cur) {
            atomicAdd(&fpsum[cur * HID + f], acc);
            acc = 0.f;
            cur = g;
        }
        acc += h[(size_t)i * HID + f];
    }
    atomicAdd(&fpsum[cur * HID + f], acc);
}

// --- final linear with mean folded in ---
__global__ void k_final(const float* __restrict__ fpsum, const int* __restrict__ gcnt,
                        const float* __restrict__ Wl, const float* __restrict__ bl,
                        float* __restrict__ out) {
    int idx = blockIdx.x * blockDim.x + threadIdx.x;
    if (idx >= N_GRAPHS * N_CLASSES) return;
    int g = idx / N_CLASSES, c = idx % N_CLASSES;
    float inv = 1.0f / (float)max(gcnt[g], 1);
    float acc = bl[c];
    for (int f = 0; f < HID; ++f)
        acc = fmaf(fpsum[g * HID + f] * inv, Wl[f * N_CLASSES + c], acc);
    out[idx] = acc;
}

extern "C" void kernel_launch(void* const* d_in, const int* in_sizes, int n_in,
                              void* d_out, int out_size, void* d_ws, size_t ws_size,
                              hipStream_t stream) {
    const float* x     = (const float*)d_in[0];
    const int*   ei    = (const int*)d_in[1];   // [2, E]: row0 = src, row1 = dst
    const int*   batch = (const int*)d_in[2];
    const float* W1 = (const float*)d_in[3];
    const float* b1 = (const float*)d_in[4];
    const float* W2 = (const float*)d_in[5];
    const float* b2 = (const float*)d_in[6];
    const float* W3 = (const float*)d_in[7];
    const float* b3 = (const float*)d_in[8];
    const float* Wl = (const float*)d_in[9];
    const float* bl = (const float*)d_in[10];
    float* out = (float*)d_out;

    const int N = N_NODES, E = N_EDGES;
    const int* srcp = ei;
    const int* dstp = ei + E;

    char* ws = (char*)d_ws;
    size_t off = 0;
    auto alloc = [&](size_t bytes) -> void* {
        void* p = ws + off;
        off += (bytes + 255) & ~(size_t)255;
        return p;
    };
    // zero-initialized region must be first & contiguous (ws is poisoned 0xAA each call)
    int*   ideg   = (int*)alloc((size_t)N * 4);
    int*   cursor = (int*)alloc((size_t)N * 4);
    float* fpsum  = (float*)alloc((size_t)N_GRAPHS * HID * 4);
    size_t zero_bytes = off;
    int*   gcnt  = (int*)alloc((size_t)N_GRAPHS * 4);
    float* dis   = (float*)alloc((size_t)N * 4);
    int*   rowst = (int*)alloc((size_t)(N + 1) * 4);
    int*   col   = (int*)alloc((size_t)E * 4);
    int*   goff  = (int*)alloc((size_t)N_GRAPHS * 4);
    int*   bsum  = (int*)alloc((size_t)SCAN_BLK * 4);
    int*   boff  = (int*)alloc((size_t)(SCAN_BLK + 1) * 4);
    float* bufA  = (float*)alloc((size_t)N * HID * 4);
    float* bufB  = (float*)alloc((size_t)N * HID * 4);

    hipMemsetAsync(d_ws, 0, zero_bytes, stream);

    const int tpb = 256;
    k_deg<<<(E + tpb - 1) / tpb, tpb, 0, stream>>>(dstp, ideg, E);
    k_dis<<<(N + tpb - 1) / tpb, tpb, 0, stream>>>(ideg, dis, N);
    k_scan_part<<<SCAN_BLK, 256, 0, stream>>>(ideg, bsum, N);
    k_scan_bsum<<<1, 256, 0, stream>>>(bsum, boff, SCAN_BLK);
    k_scan_write<<<SCAN_BLK, 256, 0, stream>>>(ideg, boff, rowst, N, SCAN_BLK);
    k_fill<<<(E + tpb - 1) / tpb, tpb, 0, stream>>>(srcp, dstp, rowst, cursor, col, E);
    k_goff<<<1, 256, 0, stream>>>(batch, goff, gcnt, N);

    // layer 1
    k_gemm_in<<<(N * HID + tpb - 1) / tpb, tpb, 0, stream>>>(x, W1, dis, bufA, N);
    k_agg<<<(N + 3) / 4, 256, 0, stream>>>(bufA, dis, rowst, col, b1, bufB);
    // layer 2
    k_gemm128<<<N / 16, 256, 0, stream>>>(bufB, W2, dis, bufA);
    k_agg<<<(N + 3) / 4, 256, 0, stream>>>(bufA, dis, rowst, col, b2, bufB);
    // layer 3
    k_gemm128<<<N / 16, 256, 0, stream>>>(bufB, W3, dis, bufA);
    k_agg<<<(N + 3) / 4, 256, 0, stream>>>(bufA, dis, rowst, col, b3, bufB);
    // pool + classifier
    k_psum<<<(N + POOL_CHUNK - 1) / POOL_CHUNK, HID, 0, stream>>>(bufB, batch, fpsum, N);
    k_final<<<(N_GRAPHS * N_CLASSES + tpb - 1) / tpb, tpb, 0, stream>>>(fpsum, gcnt, Wl, bl, out);
}

// Round 6
// 420.900 us; speedup vs baseline: 1.7913x; 1.0005x over previous
//
#include <hip/hip_runtime.h>

#define N_NODES   50000
#define N_EDGES   600000
#define HID       128
#define N_GRAPHS  128
#define N_CLASSES 5
#define POOL_CHUNK 128
#define SCAN_BLK  ((N_NODES + 255) / 256)   // 196

// --- degree (in-degree by dst, excluding self-loops) ---
__global__ void k_deg(const int* __restrict__ dst, int* __restrict__ ideg, int E) {
    int i = blockIdx.x * blockDim.x + threadIdx.x;
    if (i < E) atomicAdd(&ideg[dst[i]], 1);
}

// --- 3-phase hierarchical scan of ideg -> row_start[0..n]; dis fused into phase 1 ---
__global__ void k_scan_part(const int* __restrict__ ideg, int* __restrict__ bsum,
                            float* __restrict__ dis, int n) {
    __shared__ int s[256];
    int t = threadIdx.x;
    int i = blockIdx.x * 256 + t;
    int v = (i < n) ? ideg[i] : 0;
    if (i < n) dis[i] = 1.0f / sqrtf((float)v + 1.0f);
    s[t] = v;
    __syncthreads();
    for (int off = 128; off > 0; off >>= 1) {
        if (t < off) s[t] += s[t + off];
        __syncthreads();
    }
    if (t == 0) bsum[blockIdx.x] = s[0];
}

__global__ void k_scan_bsum(const int* __restrict__ bsum, int* __restrict__ boff, int B) {
    __shared__ int s[256];
    int t = threadIdx.x;
    int v = (t < B) ? bsum[t] : 0;
    s[t] = v;
    __syncthreads();
    for (int off = 1; off < 256; off <<= 1) {
        int u = (t >= off) ? s[t - off] : 0;
        __syncthreads();
        s[t] += u;
        __syncthreads();
    }
    if (t < B) boff[t] = s[t] - v;
    if (t == 255) boff[B] = s[255];  // grand total
}

__global__ void k_scan_write(const int* __restrict__ ideg, const int* __restrict__ boff,
                             int* __restrict__ row_start, int n, int B) {
    __shared__ int s[256];
    int t = threadIdx.x;
    int i = blockIdx.x * 256 + t;
    int v = (i < n) ? ideg[i] : 0;
    s[t] = v;
    __syncthreads();
    for (int off = 1; off < 256; off <<= 1) {
        int u = (t >= off) ? s[t - off] : 0;
        __syncthreads();
        s[t] += u;
        __syncthreads();
    }
    if (i < n) row_start[i] = boff[blockIdx.x] + s[t] - v;
    if (blockIdx.x == 0 && t == 0) row_start[n] = boff[B];
}

// --- CSR fill: col[] holds src of each incoming edge, grouped by dst ---
__global__ void k_fill(const int* __restrict__ src, const int* __restrict__ dst,
                       const int* __restrict__ row_start, int* __restrict__ cursor,
                       int* __restrict__ col, int E) {
    int i = blockIdx.x * blockDim.x + threadIdx.x;
    if (i < E) {
        int d = dst[i];
        int pos = atomicAdd(&cursor[d], 1);
        col[row_start[d] + pos] = src[i];
    }
}

// --- graph offsets via binary search on sorted batch ---
__global__ void k_goff(const int* __restrict__ batch, int* __restrict__ goff,
                       int* __restrict__ gcnt, int n) {
    __shared__ int s[N_GRAPHS + 1];
    int t = threadIdx.x;
    if (t <= N_GRAPHS) {
        int lo = 0, hi = n;
        while (lo < hi) {
            int mid = (lo + hi) >> 1;
            if (batch[mid] < t) lo = mid + 1; else hi = mid;
        }
        s[t] = lo;
        if (t < N_GRAPHS) goff[t] = lo;
    }
    __syncthreads();
    if (t < N_GRAPHS) gcnt[t] = s[t + 1] - s[t];
}

// --- layer-1 GEMM with dis pre-scale, float4 output: out[i,:] = dis[i] * (x@W1)[i,:] ---
__global__ void k_gemm_in(const float* __restrict__ x, const float* __restrict__ W,
                          const float* __restrict__ dis, float* __restrict__ out, int n) {
    int idx = blockIdx.x * blockDim.x + threadIdx.x;  // n*32 threads, 4 cols each
    if (idx >= n * 32) return;
    int row = idx >> 5, c4 = (idx & 31) * 4;
    float x0 = x[row * 3 + 0], x1 = x[row * 3 + 1], x2 = x[row * 3 + 2];
    float4 w0 = *(const float4*)&W[0 * HID + c4];
    float4 w1 = *(const float4*)&W[1 * HID + c4];
    float4 w2 = *(const float4*)&W[2 * HID + c4];
    float dd = dis[row];
    float4 o;
    o.x = dd * fmaf(x2, w2.x, fmaf(x1, w1.x, x0 * w0.x));
    o.y = dd * fmaf(x2, w2.y, fmaf(x1, w1.y, x0 * w0.y));
    o.z = dd * fmaf(x2, w2.z, fmaf(x1, w1.z, x0 * w0.z));
    o.w = dd * fmaf(x2, w2.w, fmaf(x1, w1.w, x0 * w0.w));
    *(float4*)&out[(size_t)row * HID + c4] = o;
}

// --- 128x128 GEMM, register-tiled: out = dis[:,None] * (h @ W)
// 64 rows/block, 256 threads, micro-tile 8 rows x 4 cols per thread.
// H fragments global->register (L1 broadcast: 2 distinct addrs/wave-load);
// W staged via double-buffered 4KB LDS chunk (1 ds_read_b128 feeds 32 FMAs).
__global__ __launch_bounds__(256) void k_gemm64(const float* __restrict__ h,
                                                const float* __restrict__ W,
                                                const float* __restrict__ dis,
                                                float* __restrict__ out, int n) {
    __shared__ float Ws[2][8 * HID];
    int t  = threadIdx.x;
    int tc = t & 31;        // col group: cols 4*tc .. 4*tc+3
    int tr = t >> 5;        // row group: rows row0 .. row0+7
    int rb = blockIdx.x * 64;
    int row0 = rb + tr * 8;
    int skk = t >> 5, sc4 = (t & 31) * 4;   // W staging assignment

    // stage chunk 0
    *(float4*)&Ws[0][skk * HID + sc4] = *(const float4*)&W[skk * HID + sc4];

    float acc[8][4];
#pragma unroll
    for (int r = 0; r < 8; ++r)
#pragma unroll
        for (int c = 0; c < 4; ++c) acc[r][c] = 0.f;

    int buf = 0;
    for (int k0 = 0; k0 < HID; k0 += 8) {
        // H fragment: 8 rows x 8 k, global->regs (rows clamped; stores guarded later)
        float hr[8][8];
#pragma unroll
        for (int r = 0; r < 8; ++r) {
            int row = row0 + r; if (row >= n) row = n - 1;
            const float* hp = h + (size_t)row * HID + k0;
            float4 a = *(const float4*)hp;
            float4 b = *(const float4*)(hp + 4);
            hr[r][0] = a.x; hr[r][1] = a.y; hr[r][2] = a.z; hr[r][3] = a.w;
            hr[r][4] = b.x; hr[r][5] = b.y; hr[r][6] = b.z; hr[r][7] = b.w;
        }
        __syncthreads();  // Ws[buf] staged; prev reads of Ws[buf^1] done
        if (k0 + 8 < HID)
            *(float4*)&Ws[buf ^ 1][skk * HID + sc4] =
                *(const float4*)&W[(k0 + 8 + skk) * HID + sc4];
#pragma unroll
        for (int kk = 0; kk < 8; ++kk) {
            float4 wv = *(const float4*)&Ws[buf][kk * HID + tc * 4];
#pragma unroll
            for (int r = 0; r < 8; ++r) {
                float hv = hr[r][kk];
                acc[r][0] = fmaf(hv, wv.x, acc[r][0]);
                acc[r][1] = fmaf(hv, wv.y, acc[r][1]);
                acc[r][2] = fmaf(hv, wv.z, acc[r][2]);
                acc[r][3] = fmaf(hv, wv.w, acc[r][3]);
            }
        }
        buf ^= 1;
    }
#pragma unroll
    for (int r = 0; r < 8; ++r) {
        int row = row0 + r;
        if (row < n) {
            float dd = dis[row];
            float4 o;
            o.x = dd * acc[r][0]; o.y = dd * acc[r][1];
            o.z = dd * acc[r][2]; o.w = dd * acc[r][3];
            *(float4*)&out[(size_t)row * HID + tc * 4] = o;
        }
    }
}

// --- aggregation on pre-scaled t: out[d] = relu( dis[d] * (t[d] + sum_{s in N(d)} t[s]) + b )
__global__ __launch_bounds__(256) void k_agg(const float* __restrict__ t,
                                             const float* __restrict__ dis,
                                             const int* __restrict__ row_start,
                                             const int* __restrict__ col,
                                             const float* __restrict__ bias,
                                             float* __restrict__ out) {
    int lane = threadIdx.x & 63;
    int wid  = threadIdx.x >> 6;
    int d = blockIdx.x * 4 + wid;
    if (d >= N_NODES) return;
    const float2* t2 = (const float2*)t;
    float2 bv = ((const float2*)bias)[lane];
    float dd = dis[d];
    int j0 = row_start[d], j1 = row_start[d + 1];
    float2 self = t2[(size_t)d * 64 + lane];
    float ax0 = self.x, ay0 = self.y;
    float ax1 = 0.f, ay1 = 0.f, ax2 = 0.f, ay2 = 0.f, ax3 = 0.f, ay3 = 0.f;
    int j = j0;
    for (; j + 3 < j1; j += 4) {
        int s0 = col[j], s1 = col[j + 1], s2 = col[j + 2], s3 = col[j + 3];
        float2 v0 = t2[(size_t)s0 * 64 + lane];
        float2 v1 = t2[(size_t)s1 * 64 + lane];
        float2 v2 = t2[(size_t)s2 * 64 + lane];
        float2 v3 = t2[(size_t)s3 * 64 + lane];
        ax0 += v0.x; ay0 += v0.y;
        ax1 += v1.x; ay1 += v1.y;
        ax2 += v2.x; ay2 += v2.y;
        ax3 += v3.x; ay3 += v3.y;
    }
    for (; j < j1; ++j) {
        int s = col[j];
        float2 v = t2[(size_t)s * 64 + lane];
        ax0 += v.x; ay0 += v.y;
    }
    float sx = (ax0 + ax1) + (ax2 + ax3);
    float sy = (ay0 + ay1) + (ay2 + ay3);
    float2 o;
    o.x = fmaxf(fmaf(dd, sx, bv.x), 0.f);
    o.y = fmaxf(fmaf(dd, sy, bv.y), 0.f);
    ((float2*)out)[(size_t)d * 64 + lane] = o;
}

// --- node-parallel pool partial sums ---
__global__ void k_psum(const float* __restrict__ h, const int* __restrict__ batch,
                       float* __restrict__ fpsum, int n) {
    int i0 = blockIdx.x * POOL_CHUNK;
    int f = threadIdx.x;
    int end = min(i0 + POOL_CHUNK, n);
    int cur = batch[i0];
    float acc = 0.f;
    for (int i = i0; i < end; ++i) {
        int g = batch[i];
        if (g != cur) {
            atomicAdd(&fpsum[cur * HID + f], acc);
            acc = 0.f;
            cur = g;
        }
        acc += h[(size_t)i * HID + f];
    }
    atomicAdd(&fpsum[cur * HID + f], acc);
}

// --- final linear with mean folded in ---
__global__ void k_final(const float* __restrict__ fpsum, const int* __restrict__ gcnt,
                        const float* __restrict__ Wl, const float* __restrict__ bl,
                        float* __restrict__ out) {
    int idx = blockIdx.x * blockDim.x + threadIdx.x;
    if (idx >= N_GRAPHS * N_CLASSES) return;
    int g = idx / N_CLASSES, c = idx % N_CLASSES;
    float inv = 1.0f / (float)max(gcnt[g], 1);
    float acc = bl[c];
    for (int f = 0; f < HID; ++f)
        acc = fmaf(fpsum[g * HID + f] * inv, Wl[f * N_CLASSES + c], acc);
    out[idx] = acc;
}

extern "C" void kernel_launch(void* const* d_in, const int* in_sizes, int n_in,
                              void* d_out, int out_size, void* d_ws, size_t ws_size,
                              hipStream_t stream) {
    const float* x     = (const float*)d_in[0];
    const int*   ei    = (const int*)d_in[1];   // [2, E]: row0 = src, row1 = dst
    const int*   batch = (const int*)d_in[2];
    const float* W1 = (const float*)d_in[3];
    const float* b1 = (const float*)d_in[4];
    const float* W2 = (const float*)d_in[5];
    const float* b2 = (const float*)d_in[6];
    const float* W3 = (const float*)d_in[7];
    const float* b3 = (const float*)d_in[8];
    const float* Wl = (const float*)d_in[9];
    const float* bl = (const float*)d_in[10];
    float* out = (float*)d_out;

    const int N = N_NODES, E = N_EDGES;
    const int* srcp = ei;
    const int* dstp = ei + E;

    char* ws = (char*)d_ws;
    size_t off = 0;
    auto alloc = [&](size_t bytes) -> void* {
        void* p = ws + off;
        off += (bytes + 255) & ~(size_t)255;
        return p;
    };
    // zero-initialized region must be first & contiguous (ws is poisoned 0xAA each call)
    int*   ideg   = (int*)alloc((size_t)N * 4);
    int*   cursor = (int*)alloc((size_t)N * 4);
    float* fpsum  = (float*)alloc((size_t)N_GRAPHS * HID * 4);
    size_t zero_bytes = off;
    int*   gcnt  = (int*)alloc((size_t)N_GRAPHS * 4);
    float* dis   = (float*)alloc((size_t)N * 4);
    int*   rowst = (int*)alloc((size_t)(N + 1) * 4);
    int*   col   = (int*)alloc((size_t)E * 4);
    int*   goff  = (int*)alloc((size_t)N_GRAPHS * 4);
    int*   bsum  = (int*)alloc((size_t)SCAN_BLK * 4);
    int*   boff  = (int*)alloc((size_t)(SCAN_BLK + 1) * 4);
    float* bufA  = (float*)alloc((size_t)N * HID * 4);
    float* bufB  = (float*)alloc((size_t)N * HID * 4);

    hipMemsetAsync(d_ws, 0, zero_bytes, stream);

    const int tpb = 256;
    k_deg<<<(E + tpb - 1) / tpb, tpb, 0, stream>>>(dstp, ideg, E);
    k_scan_part<<<SCAN_BLK, 256, 0, stream>>>(ideg, bsum, dis, N);
    k_scan_bsum<<<1, 256, 0, stream>>>(bsum, boff, SCAN_BLK);
    k_scan_write<<<SCAN_BLK, 256, 0, stream>>>(ideg, boff, rowst, N, SCAN_BLK);
    k_fill<<<(E + tpb - 1) / tpb, tpb, 0, stream>>>(srcp, dstp, rowst, cursor, col, E);
    k_goff<<<1, 256, 0, stream>>>(batch, goff, gcnt, N);

    // layer 1
    k_gemm_in<<<(N * 32 + tpb - 1) / tpb, tpb, 0, stream>>>(x, W1, dis, bufA, N);
    k_agg<<<(N + 3) / 4, 256, 0, stream>>>(bufA, dis, rowst, col, b1, bufB);
    // layer 2
    k_gemm64<<<(N + 63) / 64, 256, 0, stream>>>(bufB, W2, dis, bufA, N);
    k_agg<<<(N + 3) / 4, 256, 0, stream>>>(bufA, dis, rowst, col, b2, bufB);
    // layer 3
    k_gemm64<<<(N + 63) / 64, 256, 0, stream>>>(bufB, W3, dis, bufA, N);
    k_agg<<<(N + 3) / 4, 256, 0, stream>>>(bufA, dis, rowst, col, b3, bufB);
    // pool + classifier
    k_psum<<<(N + POOL_CHUNK - 1) / POOL_CHUNK, HID, 0, stream>>>(bufB, batch, fpsum, N);
    k_final<<<(N_GRAPHS * N_CLASSES + tpb - 1) / tpb, tpb, 0, stream>>>(fpsum, gcnt, Wl, bl, out);
}